// Round 13
// baseline (274.654 us; speedup 1.0000x reference)
//
#include <hip/hip_runtime.h>

// EdgeLoss: mean |sobel_mag(gray(pred)) - sobel_mag(gray(target))|
// pred/target: (32, 3, 512, 512) fp32, output: scalar fp32.
//
// Session law (R2/R5/R6/R8/R12): time ~ requested_bytes / resident_waves;
// HBM residency irrelevant (warm==cold every round); source-level MLP
// forcing refuted 3x (R3/R6/R10: held-register staging -> scratch or no
// effect). R12 (spill-proof streaming, 605MB, 41% occ) = 108.9us.
//
// R14: cut requested bytes to 1.5x minimal (302MB) AND VMEM instrs 6x.
// Full-row waves: 8 px/lane x 64 lanes = 512 cols. 4 output rows per wave
// (6 input rows). Horizontal halo = neighbor lane's gray via __shfl (R6-
// proven math, absmax 0.0) -> ZERO scalar loads (R12's 6 strided scalar
// halo loads/row-img each touched the same 16 cache lines as a float4
// wave-load). Single transient staging (6 float4 -> gray -> discard);
// only 3 gray row-sets (20 floats each) live, rotated by macro renaming.
// No dbuf, no sched_barrier, no lookahead games. 1024 blocks = 4/CU,
// 16 waves/CU; launch_bounds(256,4) pins VGPR <= 128 (4-waves/SIMD cliff).
//
// R15: identical resubmit — R14 never ran (GPUAcquisitionTimeout).

#define BATCH 32
#define HH 512
#define WW 512
#define IMG ((size_t)HH * WW)

__global__ void zero_out_kernel(float* out) { out[0] = 0.0f; }

// Sobel magnitude, same expression structure as R2..R12 (all passed):
// a = row y-1, b = row y, c = row y+1 ; 0=j-1, 1=j, 2=j+1
#define MAG(a0, a1, a2, b0, b2, c0, c1, c2)                              \
    ({ float ex_ = ((a2) - (a0)) + 2.0f * ((b2) - (b0)) + ((c2) - (c0)); \
       float ey_ = ((c0) - (a0)) + 2.0f * ((c1) - (a1)) + ((c2) - (a2)); \
       sqrtf(ex_ * ex_ + ey_ * ey_); })

// Load input row gy (both images, 3 channels, 2 float4 each = 6+6 loads),
// gray in-register, store into row-set R (Rp0..Rp7,Rpl,Rpr / Rt*).
// Branch is wave-uniform (gy uniform per wave). Staging float4s are
// transient locals -> dead after gray (no held-across-phase registers).
#define LG(R, gy_) do {                                                   \
    const int gy__ = (gy_);                                               \
    if ((unsigned)gy__ < (unsigned)HH) {                                  \
        const float* rp__ = pb + (size_t)gy__ * WW + cx;                  \
        float4 x0_ = *(const float4*)(rp__);                              \
        float4 x1_ = *(const float4*)(rp__ + 4);                          \
        float4 y0_ = *(const float4*)(rp__ + IMG);                        \
        float4 y1_ = *(const float4*)(rp__ + IMG + 4);                    \
        float4 z0_ = *(const float4*)(rp__ + 2 * IMG);                    \
        float4 z1_ = *(const float4*)(rp__ + 2 * IMG + 4);                \
        R##p0 = 0.299f * x0_.x + 0.587f * y0_.x + 0.114f * z0_.x;         \
        R##p1 = 0.299f * x0_.y + 0.587f * y0_.y + 0.114f * z0_.y;         \
        R##p2 = 0.299f * x0_.z + 0.587f * y0_.z + 0.114f * z0_.z;         \
        R##p3 = 0.299f * x0_.w + 0.587f * y0_.w + 0.114f * z0_.w;         \
        R##p4 = 0.299f * x1_.x + 0.587f * y1_.x + 0.114f * z1_.x;         \
        R##p5 = 0.299f * x1_.y + 0.587f * y1_.y + 0.114f * z1_.y;         \
        R##p6 = 0.299f * x1_.z + 0.587f * y1_.z + 0.114f * z1_.z;         \
        R##p7 = 0.299f * x1_.w + 0.587f * y1_.w + 0.114f * z1_.w;         \
        const float* rt__ = tb + (size_t)gy__ * WW + cx;                  \
        x0_ = *(const float4*)(rt__);                                     \
        x1_ = *(const float4*)(rt__ + 4);                                 \
        y0_ = *(const float4*)(rt__ + IMG);                               \
        y1_ = *(const float4*)(rt__ + IMG + 4);                           \
        z0_ = *(const float4*)(rt__ + 2 * IMG);                           \
        z1_ = *(const float4*)(rt__ + 2 * IMG + 4);                       \
        R##t0 = 0.299f * x0_.x + 0.587f * y0_.x + 0.114f * z0_.x;         \
        R##t1 = 0.299f * x0_.y + 0.587f * y0_.y + 0.114f * z0_.y;         \
        R##t2 = 0.299f * x0_.z + 0.587f * y0_.z + 0.114f * z0_.z;         \
        R##t3 = 0.299f * x0_.w + 0.587f * y0_.w + 0.114f * z0_.w;         \
        R##t4 = 0.299f * x1_.x + 0.587f * y1_.x + 0.114f * z1_.x;         \
        R##t5 = 0.299f * x1_.y + 0.587f * y1_.y + 0.114f * z1_.y;         \
        R##t6 = 0.299f * x1_.z + 0.587f * y1_.z + 0.114f * z1_.z;         \
        R##t7 = 0.299f * x1_.w + 0.587f * y1_.w + 0.114f * z1_.w;         \
    } else {                                                              \
        R##p0 = R##p1 = R##p2 = R##p3 = 0.f;                              \
        R##p4 = R##p5 = R##p6 = R##p7 = 0.f;                              \
        R##t0 = R##t1 = R##t2 = R##t3 = 0.f;                              \
        R##t4 = R##t5 = R##t6 = R##t7 = 0.f;                              \
    }                                                                     \
    { float s_;                                                           \
      s_ = __shfl_up(R##p7, 1, 64);   R##pl = (lane == 0)  ? 0.f : s_;    \
      s_ = __shfl_down(R##p0, 1, 64); R##pr = (lane == 63) ? 0.f : s_;    \
      s_ = __shfl_up(R##t7, 1, 64);   R##tl = (lane == 0)  ? 0.f : s_;    \
      s_ = __shfl_down(R##t0, 1, 64); R##tr = (lane == 63) ? 0.f : s_; }  \
} while (0)

// Sobel one output row from gray row-sets (A_=y-1, B_=y, C_=y+1), 8 px.
#define SOB(A_, B_, C_) do {                                                        \
    float ep_, et_;                                                                 \
    ep_ = MAG(A_##pl, A_##p0, A_##p1,  B_##pl, B_##p1,  C_##pl, C_##p0, C_##p1);    \
    et_ = MAG(A_##tl, A_##t0, A_##t1,  B_##tl, B_##t1,  C_##tl, C_##t0, C_##t1);    \
    lsum += fabsf(ep_ - et_);                                                       \
    ep_ = MAG(A_##p0, A_##p1, A_##p2,  B_##p0, B_##p2,  C_##p0, C_##p1, C_##p2);    \
    et_ = MAG(A_##t0, A_##t1, A_##t2,  B_##t0, B_##t2,  C_##t0, C_##t1, C_##t2);    \
    lsum += fabsf(ep_ - et_);                                                       \
    ep_ = MAG(A_##p1, A_##p2, A_##p3,  B_##p1, B_##p3,  C_##p1, C_##p2, C_##p3);    \
    et_ = MAG(A_##t1, A_##t2, A_##t3,  B_##t1, B_##t3,  C_##t1, C_##t2, C_##t3);    \
    lsum += fabsf(ep_ - et_);                                                       \
    ep_ = MAG(A_##p2, A_##p3, A_##p4,  B_##p2, B_##p4,  C_##p2, C_##p3, C_##p4);    \
    et_ = MAG(A_##t2, A_##t3, A_##t4,  B_##t2, B_##t4,  C_##t2, C_##t3, C_##t4);    \
    lsum += fabsf(ep_ - et_);                                                       \
    ep_ = MAG(A_##p3, A_##p4, A_##p5,  B_##p3, B_##p5,  C_##p3, C_##p4, C_##p5);    \
    et_ = MAG(A_##t3, A_##t4, A_##t5,  B_##t3, B_##t5,  C_##t3, C_##t4, C_##t5);    \
    lsum += fabsf(ep_ - et_);                                                       \
    ep_ = MAG(A_##p4, A_##p5, A_##p6,  B_##p4, B_##p6,  C_##p4, C_##p5, C_##p6);    \
    et_ = MAG(A_##t4, A_##t5, A_##t6,  B_##t4, B_##t6,  C_##t4, C_##t5, C_##t6);    \
    lsum += fabsf(ep_ - et_);                                                       \
    ep_ = MAG(A_##p5, A_##p6, A_##p7,  B_##p5, B_##p7,  C_##p5, C_##p6, C_##p7);    \
    et_ = MAG(A_##t5, A_##t6, A_##t7,  B_##t5, B_##t7,  C_##t5, C_##t6, C_##t7);    \
    lsum += fabsf(ep_ - et_);                                                       \
    ep_ = MAG(A_##p6, A_##p7, A_##pr,  B_##p6, B_##pr,  C_##p6, C_##p7, C_##pr);    \
    et_ = MAG(A_##t6, A_##t7, A_##tr,  B_##t6, B_##tr,  C_##t6, C_##t7, C_##tr);    \
    lsum += fabsf(ep_ - et_);                                                       \
} while (0)

__global__ __launch_bounds__(256, 4) void edge_loss_kernel(
    const float* __restrict__ pred,
    const float* __restrict__ target,
    float* __restrict__ out)
{
    const int tid  = threadIdx.x;
    const int lane = tid & 63;
    const int wav  = tid >> 6;
    const int quad = blockIdx.x * 4 + wav;   // 0..127 (4-row bands)
    const int img  = blockIdx.y;
    const int y0   = quad * 4;
    const int cx   = lane * 8;

    const float* pb = pred   + (size_t)img * 3 * IMG;
    const float* tb = target + (size_t)img * 3 * IMG;

    // 3 gray row-sets, rotated by name at each step (fully static).
    float Ap0,Ap1,Ap2,Ap3,Ap4,Ap5,Ap6,Ap7, Apl,Apr;
    float At0,At1,At2,At3,At4,At5,At6,At7, Atl,Atr;
    float Bp0,Bp1,Bp2,Bp3,Bp4,Bp5,Bp6,Bp7, Bpl,Bpr;
    float Bt0,Bt1,Bt2,Bt3,Bt4,Bt5,Bt6,Bt7, Btl,Btr;
    float Cp0,Cp1,Cp2,Cp3,Cp4,Cp5,Cp6,Cp7, Cpl,Cpr;
    float Ct0,Ct1,Ct2,Ct3,Ct4,Ct5,Ct6,Ct7, Ctl,Ctr;

    float lsum = 0.0f;

    LG(A, y0 - 1);
    LG(B, y0);
    LG(C, y0 + 1);
    SOB(A, B, C);          // output row y0
    LG(A, y0 + 2);
    SOB(B, C, A);          // output row y0+1
    LG(B, y0 + 3);
    SOB(C, A, B);          // output row y0+2
    LG(C, y0 + 4);
    SOB(A, B, C);          // output row y0+3

    // ---- reduce: wave shuffle -> one atomic per wave ----
    #pragma unroll
    for (int off = 32; off > 0; off >>= 1)
        lsum += __shfl_down(lsum, off, 64);

    if (lane == 0) {
        const float inv_n = 1.0f / ((float)BATCH * HH * WW);
        atomicAdd(out, lsum * inv_n);
    }
}

extern "C" void kernel_launch(void* const* d_in, const int* in_sizes, int n_in,
                              void* d_out, int out_size, void* d_ws, size_t ws_size,
                              hipStream_t stream) {
    const float* pred   = (const float*)d_in[0];
    const float* target = (const float*)d_in[1];
    float* out = (float*)d_out;

    // d_out is poisoned 0xAA before every timed launch -> zero it on-stream.
    zero_out_kernel<<<1, 1, 0, stream>>>(out);

    // 32 quad-groups (4 waves/block x 4-row quads) x 32 images = 1024 blocks
    // = 4 blocks/CU, 16 waves/CU. Each wave: 4 output rows, 6 input rows.
    dim3 grid(32, BATCH, 1);
    edge_loss_kernel<<<grid, 256, 0, stream>>>(pred, target, out);
}